// Round 3
// baseline (5704.240 us; speedup 1.0000x reference)
//
#include <hip/hip_runtime.h>
#include <math.h>

typedef unsigned short u16;

// Problem constants
#define Bx 8
#define Cx 64
#define Nx 128
#define Tx 288
#define PL 12          // PRED_LEN
#define CL 24          // CYCLE_LEN
#define SP 12          // SHORT_P
#define TOUT 300       // T + PRED_LEN
#define EPSV 0.01f
#define SB 8192        // series per batch (64*128)

__device__ __forceinline__ float b2f(u16 h) {
  union { unsigned int u; float f; } v; v.u = ((unsigned int)h) << 16; return v.f;
}
__device__ __forceinline__ u16 f2b(float f) {
  union { float f; unsigned int u; } v; v.f = f;
  return (u16)((v.u + 0x7FFFu + ((v.u >> 16) & 1u)) >> 16);  // RNE
}

// ---------------------------------------------------------------------------
// K0: adjacency  adjT[m][n] = softmax_m( emb[n]·emb[m] - 10*I ).  grid 128x64.
// ---------------------------------------------------------------------------
__global__ __launch_bounds__(64) void k0_adj(const float* __restrict__ emb,
                                             float* __restrict__ adjT) {
  int n = blockIdx.x;
  int lane = threadIdx.x;
  float d0 = 0.f, d1 = 0.f;
  for (int k = 0; k < 64; ++k) {
    float e = emb[n * 64 + k];
    d0 += e * emb[lane * 64 + k];
    d1 += e * emb[(lane + 64) * 64 + k];
  }
  if (lane == n) d0 -= 10.f;
  if (lane + 64 == n) d1 -= 10.f;
  float mx = fmaxf(d0, d1);
  for (int off = 32; off; off >>= 1) mx = fmaxf(mx, __shfl_xor(mx, off, 64));
  float e0 = expf(d0 - mx), e1 = expf(d1 - mx);
  float sm = e0 + e1;
  for (int off = 32; off; off >>= 1) sm += __shfl_xor(sm, off, 64);
  float inv = 1.f / sm;
  adjT[lane * 128 + n] = e0 * inv;
  adjT[(lane + 64) * 128 + n] = e1 * inv;
}

// ---------------------------------------------------------------------------
// K1: per-series norm chain for ONE batch. One wave/series; 4 series/block.
// grid 2048 x 256.  Outputs: ltm,lts,pm,ps (f32); stm,sts,x3 (bf16);
// lastx1,lastx2 (f32).
// ---------------------------------------------------------------------------
__global__ __launch_bounds__(256) void k1_chain(
    const float* __restrict__ xb, float* __restrict__ ltm, float* __restrict__ lts,
    float* __restrict__ pm, float* __restrict__ ps, u16* __restrict__ stm,
    u16* __restrict__ sts, u16* __restrict__ x3, float* __restrict__ lastx1,
    float* __restrict__ lastx2) {
  __shared__ float lds[4 * 352];
  int tid = threadIdx.x;
  int wv = tid >> 6, lane = tid & 63;
  float* buf = lds + wv * 352;   // 288 floats
  float* pat = buf + 288;        // 48 floats
  long s = (long)blockIdx.x * 4 + wv;   // 0..8191
  const float* xs = xb + s * Tx;

  float v[5];
  float sum = 0.f, sum2 = 0.f;
#pragma unroll
  for (int i = 0; i < 5; ++i) {
    int t = lane + 64 * i;
    if (t < Tx) { v[i] = xs[t]; sum += v[i]; sum2 += v[i] * v[i]; }
    else v[i] = 0.f;
  }
  for (int off = 32; off; off >>= 1) {
    sum += __shfl_xor(sum, off, 64);
    sum2 += __shfl_xor(sum2, off, 64);
  }
  float mean = sum * (1.f / 288.f);
  float var = sum2 * (1.f / 288.f) - mean * mean + 1e-5f;
  float sd = sqrtf(var);
  float r1 = rsqrtf(var + EPSV);
  if (lane == 0) { ltm[s] = mean; lts[s] = sd; }
#pragma unroll
  for (int i = 0; i < 5; ++i) {
    int t = lane + 64 * i;
    if (t < Tx) {
      float x1 = (v[i] - mean) * r1;
      v[i] = x1;
      buf[t] = x1;
      if (t >= Tx - SP) lastx1[s * SP + t - (Tx - SP)] = x1;
    }
  }
  __syncthreads();
  if (lane < CL) {
    float a = 0.f, b2 = 0.f;
    for (int k = 0; k < 12; ++k) {
      float u = buf[k * CL + lane];
      a += u; b2 += u * u;
    }
    float pmv = a * (1.f / 12.f);
    float pvar = b2 * (1.f / 12.f) - pmv * pmv + 1e-5f;
    float psd = sqrtf(pvar);
    pat[lane] = pmv; pat[CL + lane] = psd;
    pm[s * CL + lane] = pmv; ps[s * CL + lane] = psd;
  }
  __syncthreads();
  float w2v[5];
#pragma unroll
  for (int i = 0; i < 5; ++i) {
    int t = lane + 64 * i;
    if (t < Tx) {
      int l = t % CL;
      float pmv = pat[l], psd = pat[CL + l];
      float x2 = (v[i] - pmv) * rsqrtf(psd * psd + EPSV);
      w2v[i] = x2;
      if (t >= Tx - SP) lastx2[s * SP + t - (Tx - SP)] = x2;
    } else w2v[i] = 0.f;
  }
  __syncthreads();
#pragma unroll
  for (int i = 0; i < 5; ++i) {
    int t = lane + 64 * i;
    if (t < Tx) buf[t] = w2v[i];
  }
  __syncthreads();
#pragma unroll
  for (int i = 0; i < 5; ++i) {
    int t = lane + 64 * i;
    if (t < Tx) {
      int te = t < 11 ? 11 : t;
      float a = 0.f, b2 = 0.f;
#pragma unroll
      for (int jj = 0; jj < 12; ++jj) {
        float u = buf[te - 11 + jj];
        a += u; b2 += u * u;
      }
      float m = a * (1.f / 12.f);
      float varw = b2 * (1.f / 12.f) - m * m + 1e-5f;
      stm[s * Tx + t] = f2b(m);
      sts[s * Tx + t] = f2b(sqrtf(varw));
      x3[s * Tx + t] = f2b((w2v[i] - m) * rsqrtf(varw + EPSV));
    }
  }
}

// ---------------------------------------------------------------------------
// K2: spatial norm for ONE batch. grid = c*9 + tchunk (576) x 128.
// ---------------------------------------------------------------------------
__global__ __launch_bounds__(128) void k2_spatial(
    const u16* __restrict__ x3, const float* __restrict__ adjT,
    u16* __restrict__ x4, u16* __restrict__ spm, u16* __restrict__ sps) {
  __shared__ float X[128 * 36];
  int bid = blockIdx.x;
  int tc = bid % 9;
  long c = bid / 9;                 // 0..63
  int t0 = tc * 32;
  int tid = threadIdx.x;
  for (int idx = tid; idx < 128 * 32; idx += 128) {
    int m = idx >> 5, i = idx & 31;
    X[m * 36 + i] = b2f(x3[(c * 128 + m) * Tx + t0 + i]);
  }
  __syncthreads();
  float a1[32], a2[32];
#pragma unroll
  for (int i = 0; i < 32; ++i) { a1[i] = 0.f; a2[i] = 0.f; }
  for (int m = 0; m < 128; ++m) {
    float a = adjT[m * 128 + tid];
    const float4* xp = (const float4*)&X[m * 36];
#pragma unroll
    for (int ii = 0; ii < 8; ++ii) {
      float4 xq = xp[ii];
      float t0v = a * xq.x; a1[ii * 4 + 0] += t0v; a2[ii * 4 + 0] += t0v * xq.x;
      float t1v = a * xq.y; a1[ii * 4 + 1] += t1v; a2[ii * 4 + 1] += t1v * xq.y;
      float t2v = a * xq.z; a1[ii * 4 + 2] += t2v; a2[ii * 4 + 2] += t2v * xq.z;
      float t3v = a * xq.w; a1[ii * 4 + 3] += t3v; a2[ii * 4 + 3] += t3v * xq.w;
    }
  }
  long sOut = c * 128 + tid;
#pragma unroll
  for (int i = 0; i < 32; ++i) {
    float mean = a1[i];
    float varv = a2[i] - mean * mean + 1e-5f;
    float xv = X[tid * 36 + i];
    long off = sOut * Tx + t0 + i;
    x4[off] = f2b((xv - mean) * rsqrtf(varv + EPSV));
    spm[off] = f2b(mean);
    sps[off] = f2b(sqrtf(varv));
  }
}

// ---------------------------------------------------------------------------
// K3: residual-extrap tails for ONE batch. grid = j*128 + n (512) x 256.
// ---------------------------------------------------------------------------
__global__ __launch_bounds__(256) void k3_tails(
    const float* __restrict__ lastx1, const float* __restrict__ lastx2,
    const u16* __restrict__ x3, const u16* __restrict__ x4,
    const float* __restrict__ w0, const float* __restrict__ bb0,
    const float* __restrict__ w1, const float* __restrict__ bb1,
    const float* __restrict__ w2, const float* __restrict__ bb2,
    const float* __restrict__ w3, const float* __restrict__ bb3,
    float* __restrict__ tails) {
  __shared__ float S[768];
  int bid = blockIdx.x;
  int j = bid >> 7;
  int n = bid & 127;
  const float* W; const float* Bv;
  if (j == 0) { W = w0; Bv = bb0; }
  else if (j == 1) { W = w1; Bv = bb1; }
  else if (j == 2) { W = w2; Bv = bb2; }
  else { W = w3; Bv = bb3; }
  int tid = threadIdx.x;
  for (int idx = tid; idx < 768; idx += 256) {
    int cin = idx / 12, l = idx % 12;
    long s = (long)cin * 128 + n;
    float val;
    if (j == 0) val = lastx1[s * 12 + l];
    else if (j == 1) val = lastx2[s * 12 + l];
    else if (j == 2) val = b2f(x3[s * Tx + (Tx - 12) + l]);
    else val = b2f(x4[s * Tx + (Tx - 12) + l]);
    S[idx] = val;
  }
  __syncthreads();
#pragma unroll
  for (int rep = 0; rep < 3; ++rep) {
    int o = tid + rep * 256;
    float acc = Bv[o];
    const float* wr = W + (long)o * 768;
#pragma unroll 8
    for (int q = 0; q < 768; q += 4) {
      float4 wq = *(const float4*)&wr[q];
      float4 sq = *(const float4*)&S[q];
      acc += wq.x * sq.x + wq.y * sq.y + wq.z * sq.z + wq.w * sq.w;
    }
    tails[((long)j * 128 + n) * 768 + o] = acc;
  }
}

// ---------------------------------------------------------------------------
// K4: 13-block gated conv for ONE batch + fused output 1x1 convs.
// grid = n*5 + chunk (640) x 256.  LDS: slab[64][68] + wt[16][260].
// ---------------------------------------------------------------------------
__global__ __launch_bounds__(256) void k4_gated_conv(
    const float* __restrict__ xb, const float* __restrict__ ltm,
    const float* __restrict__ lts, const float* __restrict__ pm,
    const float* __restrict__ ps, const u16* __restrict__ stm,
    const u16* __restrict__ sts, const u16* __restrict__ x3,
    const u16* __restrict__ x4, const u16* __restrict__ spm,
    const u16* __restrict__ sps, const float* __restrict__ tails,
    const float* __restrict__ cw1, const float* __restrict__ cb1,
    const float* __restrict__ cw2, const float* __restrict__ cb2,
    const float* __restrict__ skw, const float* __restrict__ skb,
    const float* __restrict__ rsw, const float* __restrict__ rsb,
    float* __restrict__ outXZ, float* __restrict__ outS) {
  __shared__ float lds[8704];       // 34.8 KB
  float* slab = lds;                // [64][68], cols 0..64 used
  float* wt = lds + 64 * 68;        // [16][260]

  int bid = blockIdx.x;
  int chunk = bid % 5;
  int n = bid / 5;
  int t0 = chunk * 64;
  int tid = threadIdx.x;
  int tg = tid & 15, rg = tid >> 4;

  float acc[8][4];
#pragma unroll
  for (int rr = 0; rr < 8; ++rr) {
    int R = rg * 8 + rr;
    float bv = (R < 64) ? cb1[R] : cb2[R - 64];
#pragma unroll
    for (int d = 0; d < 4; ++d) acc[rr][d] = bv;
  }

  for (int j = 0; j < 13; ++j) {
    __syncthreads();
    // ---- stage slab: xcat block j, t = t0-1 .. t0+63 ----
    for (int idx = tid; idx < 64 * 65; idx += 256) {
      int cc = idx / 65;
      int u = idx - cc * 65;
      int t = t0 - 1 + u;
      float val = 0.f;
      if (t >= 0 && t < TOUT) {
        long s = (long)cc * 128 + n;
        int tcl = t < Tx ? t : (Tx - 1);
        switch (j) {
          case 0: val = xb[s * Tx + tcl]; break;
          case 1:
            if (t < Tx) {
              float m = ltm[s], sdv = lts[s];
              val = (xb[s * Tx + t] - m) * rsqrtf(sdv * sdv + EPSV);
            } else val = tails[((long)0 * 128 + n) * 768 + (t - Tx) * 64 + cc];
            break;
          case 2: val = ltm[s]; break;
          case 3: val = lts[s]; break;
          case 4:
            if (t < Tx) {
              float m = ltm[s], sdv = lts[s];
              float x1 = (xb[s * Tx + t] - m) * rsqrtf(sdv * sdv + EPSV);
              int l = t % CL;
              float pmv = pm[s * CL + l], psd = ps[s * CL + l];
              val = (x1 - pmv) * rsqrtf(psd * psd + EPSV);
            } else val = tails[((long)1 * 128 + n) * 768 + (t - Tx) * 64 + cc];
            break;
          case 5: val = pm[s * CL + t % CL]; break;
          case 6: val = ps[s * CL + t % CL]; break;
          case 7:
            val = (t < Tx) ? b2f(x3[s * Tx + t])
                           : tails[((long)2 * 128 + n) * 768 + (t - Tx) * 64 + cc];
            break;
          case 8: val = b2f(stm[s * Tx + tcl]); break;
          case 9: val = b2f(sts[s * Tx + tcl]); break;
          case 10:
            val = (t < Tx) ? b2f(x4[s * Tx + t])
                           : tails[((long)3 * 128 + n) * 768 + (t - Tx) * 64 + cc];
            break;
          case 11: val = b2f(spm[s * Tx + tcl]); break;
          default: val = b2f(sps[s * Tx + tcl]); break;
        }
      }
      slab[cc * 68 + u] = val;
    }
    // ---- 4 weight sub-tiles of 16 cc each ----
    for (int cs = 0; cs < 4; ++cs) {
      __syncthreads();
      {
        int base = (j * 64 + cs * 16) * 2;   // float offset within a weight row
        for (int idx = tid; idx < 2048; idx += 256) {
          int r = idx >> 4;      // 0..127
          int p = idx & 15;      // local cc
          const float* row = (r < 64) ? (cw1 + r * 1664) : (cw2 + (r - 64) * 1664);
          float2 w2 = *(const float2*)(row + base + p * 2);
          *(float2*)&wt[p * 260 + r * 2] = w2;
        }
      }
      __syncthreads();
#pragma unroll 2
      for (int ccl = 0; ccl < 16; ++ccl) {
        int cc = cs * 16 + ccl;
        const float* sp = &slab[cc * 68 + tg * 4];
        float4 xq = *(const float4*)sp;
        float xs4 = sp[4];
        const float4* wp = (const float4*)&wt[ccl * 260 + rg * 16];
        float4 wA = wp[0], wB = wp[1], wC = wp[2], wD = wp[3];
        acc[0][0] += wA.x * xq.x + wA.y * xq.y;
        acc[0][1] += wA.x * xq.y + wA.y * xq.z;
        acc[0][2] += wA.x * xq.z + wA.y * xq.w;
        acc[0][3] += wA.x * xq.w + wA.y * xs4;
        acc[1][0] += wA.z * xq.x + wA.w * xq.y;
        acc[1][1] += wA.z * xq.y + wA.w * xq.z;
        acc[1][2] += wA.z * xq.z + wA.w * xq.w;
        acc[1][3] += wA.z * xq.w + wA.w * xs4;
        acc[2][0] += wB.x * xq.x + wB.y * xq.y;
        acc[2][1] += wB.x * xq.y + wB.y * xq.z;
        acc[2][2] += wB.x * xq.z + wB.y * xq.w;
        acc[2][3] += wB.x * xq.w + wB.y * xs4;
        acc[3][0] += wB.z * xq.x + wB.w * xq.y;
        acc[3][1] += wB.z * xq.y + wB.w * xq.z;
        acc[3][2] += wB.z * xq.z + wB.w * xq.w;
        acc[3][3] += wB.z * xq.w + wB.w * xs4;
        acc[4][0] += wC.x * xq.x + wC.y * xq.y;
        acc[4][1] += wC.x * xq.y + wC.y * xq.z;
        acc[4][2] += wC.x * xq.z + wC.y * xq.w;
        acc[4][3] += wC.x * xq.w + wC.y * xs4;
        acc[5][0] += wC.z * xq.x + wC.w * xq.y;
        acc[5][1] += wC.z * xq.y + wC.w * xq.z;
        acc[5][2] += wC.z * xq.z + wC.w * xq.w;
        acc[5][3] += wC.z * xq.w + wC.w * xs4;
        acc[6][0] += wD.x * xq.x + wD.y * xq.y;
        acc[6][1] += wD.x * xq.y + wD.y * xq.z;
        acc[6][2] += wD.x * xq.z + wD.y * xq.w;
        acc[6][3] += wD.x * xq.w + wD.y * xs4;
        acc[7][0] += wD.z * xq.x + wD.w * xq.y;
        acc[7][1] += wD.z * xq.y + wD.w * xq.z;
        acc[7][2] += wD.z * xq.z + wD.w * xq.w;
        acc[7][3] += wD.z * xq.w + wD.w * xs4;
      }
    }
  }

  // ---- epilogue: z = tanh(a1)*sigmoid(a2), then 1x1 convs ----
  __syncthreads();
#pragma unroll
  for (int rr = 0; rr < 8; ++rr)
#pragma unroll
    for (int d = 0; d < 4; ++d)
      lds[(rg * 8 + rr) * 68 + tg * 4 + d] = acc[rr][d];
  __syncthreads();
  if (rg < 8) {
#pragma unroll
    for (int rr = 0; rr < 8; ++rr) {
      int R = rg * 8 + rr;
#pragma unroll
      for (int d = 0; d < 4; ++d) {
        float a2v = lds[(R + 64) * 68 + tg * 4 + d];
        lds[R * 68 + tg * 4 + d] =
            tanhf(acc[rr][d]) * (1.f / (1.f + expf(-a2v)));
      }
    }
  }
  __syncthreads();
  int tbase = t0 + tg * 4;
  if (tbase < TOUT) {
    bool sk = tbase >= Tx;
    const float* wsel = sk ? skw : rsw;
    const float* bsel = sk ? skb : rsb;
    float oacc[4][4];
#pragma unroll
    for (int q = 0; q < 4; ++q) {
      float bv = bsel[rg * 4 + q];
#pragma unroll
      for (int d = 0; d < 4; ++d) oacc[q][d] = bv;
    }
    for (int o = 0; o < 64; ++o) {
      const float4 zq = *(const float4*)&lds[o * 68 + tg * 4];
#pragma unroll
      for (int q = 0; q < 4; ++q) {
        float wv = wsel[(rg * 4 + q) * 64 + o];
        oacc[q][0] += wv * zq.x;
        oacc[q][1] += wv * zq.y;
        oacc[q][2] += wv * zq.z;
        oacc[q][3] += wv * zq.w;
      }
    }
    if (!sk) {
#pragma unroll
      for (int q = 0; q < 4; ++q) {
        long off = ((long)(rg * 4 + q) * 128 + n) * (long)Tx + tbase;
        *(float4*)&outXZ[off] = make_float4(oacc[q][0], oacc[q][1], oacc[q][2], oacc[q][3]);
      }
    } else {
      int tt = tbase - Tx;
#pragma unroll
      for (int q = 0; q < 4; ++q) {
        long off = ((long)(rg * 4 + q) * 128 + n) * (long)PL + tt;
        *(float4*)&outS[off] = make_float4(oacc[q][0], oacc[q][1], oacc[q][2], oacc[q][3]);
      }
    }
  }
}

// ---------------------------------------------------------------------------
extern "C" void kernel_launch(void* const* d_in, const int* in_sizes, int n_in,
                              void* d_out, int out_size, void* d_ws, size_t ws_size,
                              hipStream_t stream) {
  const float* x   = (const float*)d_in[0];
  const float* emb = (const float*)d_in[1];
  const float* rew[4] = {(const float*)d_in[2], (const float*)d_in[4],
                         (const float*)d_in[6], (const float*)d_in[8]};
  const float* reb[4] = {(const float*)d_in[3], (const float*)d_in[5],
                         (const float*)d_in[7], (const float*)d_in[9]};
  const float* c1w = (const float*)d_in[10];
  const float* c1b = (const float*)d_in[11];
  const float* c2w = (const float*)d_in[12];
  const float* c2b = (const float*)d_in[13];
  const float* skw = (const float*)d_in[14];
  const float* skb = (const float*)d_in[15];
  const float* rsw = (const float*)d_in[16];
  const float* rsb = (const float*)d_in[17];
  float* out = (float*)d_out;

  // per-batch workspace layout — ~32.4 MB total
  const long NTb = (long)SB * Tx;            // 2,359,296
  float* ws = (float*)d_ws;
  float* adjT   = ws;                        // 16384 f32
  float* ltm    = adjT + 16384;              // 8192 f32
  float* lts    = ltm + SB;                  // 8192 f32
  float* pmv    = lts + SB;                  // SB*24 f32
  float* psv    = pmv + (long)SB * CL;       // SB*24 f32
  float* lastx1 = psv + (long)SB * CL;       // SB*12 f32
  float* lastx2 = lastx1 + (long)SB * SP;    // SB*12 f32
  float* tails  = lastx2 + (long)SB * SP;    // 4*128*768 f32
  u16* u16base  = (u16*)(tails + (long)4 * 128 * 768);
  u16* stm = u16base;                        // NTb u16
  u16* sts = stm + NTb;
  u16* x3  = sts + NTb;
  u16* x4  = x3 + NTb;
  u16* spm = x4 + NTb;
  u16* sps = spm + NTb;

  hipLaunchKernelGGL(k0_adj, dim3(128), dim3(64), 0, stream, emb, adjT);
  for (int b = 0; b < Bx; ++b) {
    const float* xbp = x + (long)b * 64 * 128 * Tx;
    float* oXZ = out + (long)b * 64 * 128 * Tx;
    float* oS  = out + (long)Bx * 64 * 128 * Tx + (long)b * 64 * 128 * PL;
    hipLaunchKernelGGL(k1_chain, dim3(2048), dim3(256), 0, stream,
                       xbp, ltm, lts, pmv, psv, stm, sts, x3, lastx1, lastx2);
    hipLaunchKernelGGL(k2_spatial, dim3(576), dim3(128), 0, stream,
                       x3, adjT, x4, spm, sps);
    hipLaunchKernelGGL(k3_tails, dim3(512), dim3(256), 0, stream,
                       lastx1, lastx2, x3, x4,
                       rew[0], reb[0], rew[1], reb[1],
                       rew[2], reb[2], rew[3], reb[3], tails);
    hipLaunchKernelGGL(k4_gated_conv, dim3(640), dim3(256), 0, stream,
                       xbp, ltm, lts, pmv, psv, stm, sts, x3, x4, spm, sps, tails,
                       c1w, c1b, c2w, c2b, skw, skb, rsw, rsb, oXZ, oS);
  }
}

// Round 4
// 3473.011 us; speedup vs baseline: 1.6424x; 1.6424x over previous
//
#include <hip/hip_runtime.h>
#include <math.h>

typedef unsigned short u16;
typedef unsigned int u32;
typedef __attribute__((ext_vector_type(8))) short s8v;   // 8 bf16 (4 VGPR)
typedef __attribute__((ext_vector_type(4))) float f4v;   // mfma acc

// Problem constants
#define Bx 8
#define Cx 64
#define Nx 128
#define Tx 288
#define PL 12
#define CL 24
#define SP 12
#define TOUT 300
#define EPSV 0.01f
#define SB 8192

__device__ __forceinline__ float b2f(u16 h) {
  union { u32 u; float f; } v; v.u = ((u32)h) << 16; return v.f;
}
__device__ __forceinline__ u16 f2b(float f) {
  union { float f; u32 u; } v; v.f = f;
  return (u16)((v.u + 0x7FFFu + ((v.u >> 16) & 1u)) >> 16);  // RNE
}

// ---------------------------------------------------------------------------
// K0: adjacency  adjT[m][n] = softmax_m( emb[n]·emb[m] - 10*I ).  grid 128x64.
// ---------------------------------------------------------------------------
__global__ __launch_bounds__(64) void k0_adj(const float* __restrict__ emb,
                                             float* __restrict__ adjT) {
  int n = blockIdx.x;
  int lane = threadIdx.x;
  float d0 = 0.f, d1 = 0.f;
  for (int k = 0; k < 64; ++k) {
    float e = emb[n * 64 + k];
    d0 += e * emb[lane * 64 + k];
    d1 += e * emb[(lane + 64) * 64 + k];
  }
  if (lane == n) d0 -= 10.f;
  if (lane + 64 == n) d1 -= 10.f;
  float mx = fmaxf(d0, d1);
  for (int off = 32; off; off >>= 1) mx = fmaxf(mx, __shfl_xor(mx, off, 64));
  float e0 = expf(d0 - mx), e1 = expf(d1 - mx);
  float sm = e0 + e1;
  for (int off = 32; off; off >>= 1) sm += __shfl_xor(sm, off, 64);
  float inv = 1.f / sm;
  adjT[lane * 128 + n] = e0 * inv;
  adjT[(lane + 64) * 128 + n] = e1 * inv;
}

// ---------------------------------------------------------------------------
// Kw: weight prep (once).  W16[R][j*128 + tap*64 + cc] = bf16(cw[R][(j*64+cc)*2+tap])
// rows 0..63 = conv1, 64..127 = conv2.  Also 1x1 weights -> bf16 [o][r].
// grid 128 x 256.
// ---------------------------------------------------------------------------
__global__ __launch_bounds__(256) void k_wprep(
    const float* __restrict__ cw1, const float* __restrict__ cw2,
    const float* __restrict__ rsw, const float* __restrict__ skw,
    u16* __restrict__ W16, u16* __restrict__ WR16, u16* __restrict__ WS16) {
  int R = blockIdx.x;
  const float* src = (R < 64) ? (cw1 + (long)R * 1664) : (cw2 + (long)(R - 64) * 1664);
  for (int k = threadIdx.x; k < 1664; k += 256) {
    int j = k >> 7, rem = k & 127, tap = rem >> 6, cc = rem & 63;
    W16[(long)R * 1664 + k] = f2b(src[(j * 64 + cc) * 2 + tap]);
  }
  if (R < 64 && threadIdx.x < 64) {
    WR16[R * 64 + threadIdx.x] = f2b(rsw[R * 64 + threadIdx.x]);
    WS16[R * 64 + threadIdx.x] = f2b(skw[R * 64 + threadIdx.x]);
  }
}

// ---------------------------------------------------------------------------
// K1: per-series norm chain for ONE batch (unchanged from round 3).
// ---------------------------------------------------------------------------
__global__ __launch_bounds__(256) void k1_chain(
    const float* __restrict__ xb, float* __restrict__ ltm, float* __restrict__ lts,
    float* __restrict__ pm, float* __restrict__ ps, u16* __restrict__ stm,
    u16* __restrict__ sts, u16* __restrict__ x3, float* __restrict__ lastx1,
    float* __restrict__ lastx2) {
  __shared__ float lds[4 * 352];
  int tid = threadIdx.x;
  int wv = tid >> 6, lane = tid & 63;
  float* buf = lds + wv * 352;
  float* pat = buf + 288;
  long s = (long)blockIdx.x * 4 + wv;
  const float* xs = xb + s * Tx;

  float v[5];
  float sum = 0.f, sum2 = 0.f;
#pragma unroll
  for (int i = 0; i < 5; ++i) {
    int t = lane + 64 * i;
    if (t < Tx) { v[i] = xs[t]; sum += v[i]; sum2 += v[i] * v[i]; }
    else v[i] = 0.f;
  }
  for (int off = 32; off; off >>= 1) {
    sum += __shfl_xor(sum, off, 64);
    sum2 += __shfl_xor(sum2, off, 64);
  }
  float mean = sum * (1.f / 288.f);
  float var = sum2 * (1.f / 288.f) - mean * mean + 1e-5f;
  float sd = sqrtf(var);
  float r1 = rsqrtf(var + EPSV);
  if (lane == 0) { ltm[s] = mean; lts[s] = sd; }
#pragma unroll
  for (int i = 0; i < 5; ++i) {
    int t = lane + 64 * i;
    if (t < Tx) {
      float x1 = (v[i] - mean) * r1;
      v[i] = x1;
      buf[t] = x1;
      if (t >= Tx - SP) lastx1[s * SP + t - (Tx - SP)] = x1;
    }
  }
  __syncthreads();
  if (lane < CL) {
    float a = 0.f, b2 = 0.f;
    for (int k = 0; k < 12; ++k) {
      float u = buf[k * CL + lane];
      a += u; b2 += u * u;
    }
    float pmv = a * (1.f / 12.f);
    float pvar = b2 * (1.f / 12.f) - pmv * pmv + 1e-5f;
    float psd = sqrtf(pvar);
    pat[lane] = pmv; pat[CL + lane] = psd;
    pm[s * CL + lane] = pmv; ps[s * CL + lane] = psd;
  }
  __syncthreads();
  float w2v[5];
#pragma unroll
  for (int i = 0; i < 5; ++i) {
    int t = lane + 64 * i;
    if (t < Tx) {
      int l = t % CL;
      float pmv = pat[l], psd = pat[CL + l];
      float x2 = (v[i] - pmv) * rsqrtf(psd * psd + EPSV);
      w2v[i] = x2;
      if (t >= Tx - SP) lastx2[s * SP + t - (Tx - SP)] = x2;
    } else w2v[i] = 0.f;
  }
  __syncthreads();
#pragma unroll
  for (int i = 0; i < 5; ++i) {
    int t = lane + 64 * i;
    if (t < Tx) buf[t] = w2v[i];
  }
  __syncthreads();
#pragma unroll
  for (int i = 0; i < 5; ++i) {
    int t = lane + 64 * i;
    if (t < Tx) {
      int te = t < 11 ? 11 : t;
      float a = 0.f, b2 = 0.f;
#pragma unroll
      for (int jj = 0; jj < 12; ++jj) {
        float u = buf[te - 11 + jj];
        a += u; b2 += u * u;
      }
      float m = a * (1.f / 12.f);
      float varw = b2 * (1.f / 12.f) - m * m + 1e-5f;
      stm[s * Tx + t] = f2b(m);
      sts[s * Tx + t] = f2b(sqrtf(varw));
      x3[s * Tx + t] = f2b((w2v[i] - m) * rsqrtf(varw + EPSV));
    }
  }
}

// ---------------------------------------------------------------------------
// K2: spatial norm (unchanged from round 3).
// ---------------------------------------------------------------------------
__global__ __launch_bounds__(128) void k2_spatial(
    const u16* __restrict__ x3, const float* __restrict__ adjT,
    u16* __restrict__ x4, u16* __restrict__ spm, u16* __restrict__ sps) {
  __shared__ float X[128 * 36];
  int bid = blockIdx.x;
  int tc = bid % 9;
  long c = bid / 9;
  int t0 = tc * 32;
  int tid = threadIdx.x;
  for (int idx = tid; idx < 128 * 32; idx += 128) {
    int m = idx >> 5, i = idx & 31;
    X[m * 36 + i] = b2f(x3[(c * 128 + m) * Tx + t0 + i]);
  }
  __syncthreads();
  float a1[32], a2[32];
#pragma unroll
  for (int i = 0; i < 32; ++i) { a1[i] = 0.f; a2[i] = 0.f; }
  for (int m = 0; m < 128; ++m) {
    float a = adjT[m * 128 + tid];
    const float4* xp = (const float4*)&X[m * 36];
#pragma unroll
    for (int ii = 0; ii < 8; ++ii) {
      float4 xq = xp[ii];
      float t0v = a * xq.x; a1[ii * 4 + 0] += t0v; a2[ii * 4 + 0] += t0v * xq.x;
      float t1v = a * xq.y; a1[ii * 4 + 1] += t1v; a2[ii * 4 + 1] += t1v * xq.y;
      float t2v = a * xq.z; a1[ii * 4 + 2] += t2v; a2[ii * 4 + 2] += t2v * xq.z;
      float t3v = a * xq.w; a1[ii * 4 + 3] += t3v; a2[ii * 4 + 3] += t3v * xq.w;
    }
  }
  long sOut = c * 128 + tid;
#pragma unroll
  for (int i = 0; i < 32; ++i) {
    float mean = a1[i];
    float varv = a2[i] - mean * mean + 1e-5f;
    float xv = X[tid * 36 + i];
    long off = sOut * Tx + t0 + i;
    x4[off] = f2b((xv - mean) * rsqrtf(varv + EPSV));
    spm[off] = f2b(mean);
    sps[off] = f2b(sqrtf(varv));
  }
}

// ---------------------------------------------------------------------------
// K3: residual-extrap tails (unchanged from round 3).
// ---------------------------------------------------------------------------
__global__ __launch_bounds__(256) void k3_tails(
    const float* __restrict__ lastx1, const float* __restrict__ lastx2,
    const u16* __restrict__ x3, const u16* __restrict__ x4,
    const float* __restrict__ w0, const float* __restrict__ bb0,
    const float* __restrict__ w1, const float* __restrict__ bb1,
    const float* __restrict__ w2, const float* __restrict__ bb2,
    const float* __restrict__ w3, const float* __restrict__ bb3,
    float* __restrict__ tails) {
  __shared__ float S[768];
  int bid = blockIdx.x;
  int j = bid >> 7;
  int n = bid & 127;
  const float* W; const float* Bv;
  if (j == 0) { W = w0; Bv = bb0; }
  else if (j == 1) { W = w1; Bv = bb1; }
  else if (j == 2) { W = w2; Bv = bb2; }
  else { W = w3; Bv = bb3; }
  int tid = threadIdx.x;
  for (int idx = tid; idx < 768; idx += 256) {
    int cin = idx / 12, l = idx % 12;
    long s = (long)cin * 128 + n;
    float val;
    if (j == 0) val = lastx1[s * 12 + l];
    else if (j == 1) val = lastx2[s * 12 + l];
    else if (j == 2) val = b2f(x3[s * Tx + (Tx - 12) + l]);
    else val = b2f(x4[s * Tx + (Tx - 12) + l]);
    S[idx] = val;
  }
  __syncthreads();
#pragma unroll
  for (int rep = 0; rep < 3; ++rep) {
    int o = tid + rep * 256;
    float acc = Bv[o];
    const float* wr = W + (long)o * 768;
#pragma unroll 8
    for (int q = 0; q < 768; q += 4) {
      float4 wq = *(const float4*)&wr[q];
      float4 sq = *(const float4*)&S[q];
      acc += wq.x * sq.x + wq.y * sq.y + wq.z * sq.z + wq.w * sq.w;
    }
    tails[((long)j * 128 + n) * 768 + o] = acc;
  }
}

// ---------------------------------------------------------------------------
// xcat value generator (per j-block), identical math to round 3.
// ---------------------------------------------------------------------------
__device__ __forceinline__ float xcat_val(
    int j, int cc, int n, int tg,
    const float* __restrict__ xb, const float* __restrict__ ltm,
    const float* __restrict__ lts, const float* __restrict__ pm,
    const float* __restrict__ ps, const u16* __restrict__ stm,
    const u16* __restrict__ sts, const u16* __restrict__ x3,
    const u16* __restrict__ x4, const u16* __restrict__ spm,
    const u16* __restrict__ sps, const float* __restrict__ tails) {
  if (tg < 0 || tg >= TOUT) return 0.f;
  long s = (long)cc * 128 + n;
  int tcl = tg < Tx ? tg : (Tx - 1);
  switch (j) {
    case 0: return xb[s * Tx + tcl];
    case 1:
      if (tg < Tx) {
        float m = ltm[s], sdv = lts[s];
        return (xb[s * Tx + tg] - m) * rsqrtf(sdv * sdv + EPSV);
      }
      return tails[((long)0 * 128 + n) * 768 + (tg - Tx) * 64 + cc];
    case 2: return ltm[s];
    case 3: return lts[s];
    case 4:
      if (tg < Tx) {
        float m = ltm[s], sdv = lts[s];
        float x1 = (xb[s * Tx + tg] - m) * rsqrtf(sdv * sdv + EPSV);
        int l = tg % CL;
        float pmv = pm[s * CL + l], psd = ps[s * CL + l];
        return (x1 - pmv) * rsqrtf(psd * psd + EPSV);
      }
      return tails[((long)1 * 128 + n) * 768 + (tg - Tx) * 64 + cc];
    case 5: return pm[s * CL + tg % CL];
    case 6: return ps[s * CL + tg % CL];
    case 7:
      return (tg < Tx) ? b2f(x3[s * Tx + tg])
                       : tails[((long)2 * 128 + n) * 768 + (tg - Tx) * 64 + cc];
    case 8: return b2f(stm[s * Tx + tcl]);
    case 9: return b2f(sts[s * Tx + tcl]);
    case 10:
      return (tg < Tx) ? b2f(x4[s * Tx + tg])
                       : tails[((long)3 * 128 + n) * 768 + (tg - Tx) * 64 + cc];
    case 11: return b2f(spm[s * Tx + tcl]);
    default: return b2f(sps[s * Tx + tcl]);
  }
}

// ---------------------------------------------------------------------------
// K4 (MFMA): gated conv as bf16 GEMM, M=128 rows x N=128 t x K=1664,
// + fused tanh*sigmoid + both 1x1 convs via a second small MFMA GEMM.
// grid (per batch) = chunk*128 + n : 384 blocks x 256 threads (4 waves).
// Wave wv: rh=wv>>1 row-half (64 rows), th=wv&1 t-half (64 t): 4x4 C-tiles.
// LDS: Bb u16[128][136] (t-major, k=tap*64+cc, pad+8) = 34816 B, then reused
// as abuf f32[64][132] (a2 exchange) + zB u16[128][72].
// ---------------------------------------------------------------------------
__global__ __launch_bounds__(256) void k4_mfma(
    const float* __restrict__ xb, const float* __restrict__ ltm,
    const float* __restrict__ lts, const float* __restrict__ pm,
    const float* __restrict__ ps, const u16* __restrict__ stm,
    const u16* __restrict__ sts, const u16* __restrict__ x3,
    const u16* __restrict__ x4, const u16* __restrict__ spm,
    const u16* __restrict__ sps, const float* __restrict__ tails,
    const u16* __restrict__ W16, const u16* __restrict__ WR16,
    const u16* __restrict__ WS16, const float* __restrict__ cb1,
    const float* __restrict__ cb2, const float* __restrict__ rsb,
    const float* __restrict__ skb,
    float* __restrict__ outXZ, float* __restrict__ outS) {
  __shared__ float smemf[13056];            // 52224 B
  u16* Bb = (u16*)smemf;                    // [128][136] bf16 (phase 1)
  float* abuf = smemf;                      // [64][132] f32 (phase 2)
  u16* zB = (u16*)(smemf + 8448);           // [128][72] bf16 (phase 2/3)

  int bid = blockIdx.x;
  int n = bid & 127;
  int chunk = bid >> 7;                     // 0..2
  int t0 = chunk * 128;
  int tid = threadIdx.x;
  int wv = tid >> 6, lane = tid & 63;
  int rh = wv >> 1, th = wv & 1;
  int rlane = lane & 15, glane = lane >> 4;
  int klane = glane * 8;

  // acc init with conv biases: C/D row = glane*4 + reg
  f4v acc[4][4];
#pragma unroll
  for (int rt = 0; rt < 4; ++rt) {
    int Rb = rh * 64 + rt * 16 + glane * 4;
#pragma unroll
    for (int reg = 0; reg < 4; ++reg) {
      int R = Rb + reg;
      float bv = (R < 64) ? cb1[R] : cb2[R - 64];
#pragma unroll
      for (int ct = 0; ct < 4; ++ct) acc[rt][ct][reg] = bv;
    }
  }

  for (int j = 0; j < 13; ++j) {
    __syncthreads();
    // ---- stage Bb: for cc-pair, u in 0..128 (tglob = t0-1+u) ----
    for (int idx = tid; idx < 32 * 129; idx += 256) {
      int ccp = idx / 129;
      int u = idx - ccp * 129;
      int cc0 = ccp * 2;
      int tg = t0 - 1 + u;
      float v0 = xcat_val(j, cc0, n, tg, xb, ltm, lts, pm, ps, stm, sts, x3, x4, spm, sps, tails);
      float v1 = xcat_val(j, cc0 + 1, n, tg, xb, ltm, lts, pm, ps, stm, sts, x3, x4, spm, sps, tails);
      u32 w = (u32)f2b(v0) | ((u32)f2b(v1) << 16);
      if (u >= 1)  *(u32*)&Bb[(u - 1) * 136 + 64 + cc0] = w;   // tap1 at t=tg
      if (u < 128) *(u32*)&Bb[u * 136 + cc0] = w;              // tap0 at t=tg+1
    }
    __syncthreads();
    // ---- 4 k-steps of 32 ----
#pragma unroll
    for (int kc = 0; kc < 4; ++kc) {
      int kb = j * 128 + kc * 32 + klane;
      s8v av[4], bv[4];
#pragma unroll
      for (int rt = 0; rt < 4; ++rt) {
        int R = rh * 64 + rt * 16 + rlane;
        av[rt] = *(const s8v*)(W16 + (long)R * 1664 + kb);
      }
#pragma unroll
      for (int ct = 0; ct < 4; ++ct) {
        int tl = th * 64 + ct * 16 + rlane;
        bv[ct] = *(const s8v*)(Bb + tl * 136 + kc * 32 + klane);
      }
#pragma unroll
      for (int rt = 0; rt < 4; ++rt)
#pragma unroll
        for (int ct = 0; ct < 4; ++ct)
          acc[rt][ct] = __builtin_amdgcn_mfma_f32_16x16x32_bf16(av[rt], bv[ct], acc[rt][ct], 0, 0, 0);
    }
  }

  // ---- epilogue ----
  __syncthreads();
  if (rh == 1) {  // conv2 rows -> a2 to LDS
#pragma unroll
    for (int rt = 0; rt < 4; ++rt)
#pragma unroll
      for (int ct = 0; ct < 4; ++ct)
#pragma unroll
        for (int reg = 0; reg < 4; ++reg) {
          int r = rt * 16 + glane * 4 + reg;
          int tl = th * 64 + ct * 16 + rlane;
          abuf[r * 132 + tl] = acc[rt][ct][reg];
        }
  }
  __syncthreads();
  if (rh == 0) {  // z = tanh(a1)*sigmoid(a2) -> zB bf16 [t][r]
#pragma unroll
    for (int rt = 0; rt < 4; ++rt)
#pragma unroll
      for (int ct = 0; ct < 4; ++ct)
#pragma unroll
        for (int reg = 0; reg < 4; ++reg) {
          int r = rt * 16 + glane * 4 + reg;
          int tl = th * 64 + ct * 16 + rlane;
          float a2v = abuf[r * 132 + tl];
          float z = tanhf(acc[rt][ct][reg]) * (1.f / (1.f + expf(-a2v)));
          zB[tl * 72 + r] = f2b(z);
        }
  }
  __syncthreads();
  // ---- out GEMM: wave wv handles o-tile wv (16 o), 8 t-tiles, K=64 ----
  {
    int oL = wv * 16 + rlane;       // A-load row
    int oS = wv * 16 + glane * 4;   // store row base
    s8v aR0 = *(const s8v*)(WR16 + oL * 64 + klane);
    s8v aR1 = *(const s8v*)(WR16 + oL * 64 + 32 + klane);
    s8v aS0 = *(const s8v*)(WS16 + oL * 64 + klane);
    s8v aS1 = *(const s8v*)(WS16 + oL * 64 + 32 + klane);
#pragma unroll
    for (int tt = 0; tt < 8; ++tt) {
      int tstart = t0 + tt * 16;
      if (tstart >= TOUT) break;
      bool res = tstart < Tx;
      s8v b0 = *(const s8v*)(zB + (tt * 16 + rlane) * 72 + klane);
      s8v b1 = *(const s8v*)(zB + (tt * 16 + rlane) * 72 + 32 + klane);
      f4v oa;
#pragma unroll
      for (int reg = 0; reg < 4; ++reg)
        oa[reg] = res ? rsb[oS + reg] : skb[oS + reg];
      if (res) {
        oa = __builtin_amdgcn_mfma_f32_16x16x32_bf16(aR0, b0, oa, 0, 0, 0);
        oa = __builtin_amdgcn_mfma_f32_16x16x32_bf16(aR1, b1, oa, 0, 0, 0);
        int tglob = tstart + rlane;
#pragma unroll
        for (int reg = 0; reg < 4; ++reg)
          outXZ[((long)(oS + reg) * 128 + n) * Tx + tglob] = oa[reg];
      } else {
        oa = __builtin_amdgcn_mfma_f32_16x16x32_bf16(aS0, b0, oa, 0, 0, 0);
        oa = __builtin_amdgcn_mfma_f32_16x16x32_bf16(aS1, b1, oa, 0, 0, 0);
        int tglob = tstart + rlane;
        if (tglob < TOUT) {
#pragma unroll
          for (int reg = 0; reg < 4; ++reg)
            outS[((long)(oS + reg) * 128 + n) * PL + (tglob - Tx)] = oa[reg];
        }
      }
    }
  }
}

// ---------------------------------------------------------------------------
extern "C" void kernel_launch(void* const* d_in, const int* in_sizes, int n_in,
                              void* d_out, int out_size, void* d_ws, size_t ws_size,
                              hipStream_t stream) {
  const float* x   = (const float*)d_in[0];
  const float* emb = (const float*)d_in[1];
  const float* rew[4] = {(const float*)d_in[2], (const float*)d_in[4],
                         (const float*)d_in[6], (const float*)d_in[8]};
  const float* reb[4] = {(const float*)d_in[3], (const float*)d_in[5],
                         (const float*)d_in[7], (const float*)d_in[9]};
  const float* c1w = (const float*)d_in[10];
  const float* c1b = (const float*)d_in[11];
  const float* c2w = (const float*)d_in[12];
  const float* c2b = (const float*)d_in[13];
  const float* skw = (const float*)d_in[14];
  const float* skb = (const float*)d_in[15];
  const float* rsw = (const float*)d_in[16];
  const float* rsb = (const float*)d_in[17];
  float* out = (float*)d_out;

  // per-batch workspace (~32.9 MB)
  const long NTb = (long)SB * Tx;
  float* ws = (float*)d_ws;
  float* adjT   = ws;                        // 16384 f32
  float* ltm    = adjT + 16384;
  float* lts    = ltm + SB;
  float* pmv    = lts + SB;
  float* psv    = pmv + (long)SB * CL;
  float* lastx1 = psv + (long)SB * CL;
  float* lastx2 = lastx1 + (long)SB * SP;
  float* tails  = lastx2 + (long)SB * SP;    // 4*128*768 f32
  u16* u16base  = (u16*)(tails + (long)4 * 128 * 768);
  u16* stm = u16base;                        // NTb each
  u16* sts = stm + NTb;
  u16* x3  = sts + NTb;
  u16* x4  = x3 + NTb;
  u16* spm = x4 + NTb;
  u16* sps = spm + NTb;
  u16* W16  = sps + NTb;                     // 128*1664
  u16* WR16 = W16 + (long)128 * 1664;        // 64*64
  u16* WS16 = WR16 + 4096;                   // 64*64

  hipLaunchKernelGGL(k0_adj, dim3(128), dim3(64), 0, stream, emb, adjT);
  hipLaunchKernelGGL(k_wprep, dim3(128), dim3(256), 0, stream,
                     c1w, c2w, rsw, skw, W16, WR16, WS16);
  for (int b = 0; b < Bx; ++b) {
    const float* xbp = x + (long)b * 64 * 128 * Tx;
    float* oXZ = out + (long)b * 64 * 128 * Tx;
    float* oS  = out + (long)Bx * 64 * 128 * Tx + (long)b * 64 * 128 * PL;
    hipLaunchKernelGGL(k1_chain, dim3(2048), dim3(256), 0, stream,
                       xbp, ltm, lts, pmv, psv, stm, sts, x3, lastx1, lastx2);
    hipLaunchKernelGGL(k2_spatial, dim3(576), dim3(128), 0, stream,
                       x3, adjT, x4, spm, sps);
    hipLaunchKernelGGL(k3_tails, dim3(512), dim3(256), 0, stream,
                       lastx1, lastx2, x3, x4,
                       rew[0], reb[0], rew[1], reb[1],
                       rew[2], reb[2], rew[3], reb[3], tails);
    hipLaunchKernelGGL(k4_mfma, dim3(384), dim3(256), 0, stream,
                       xbp, ltm, lts, pmv, psv, stm, sts, x3, x4, spm, sps, tails,
                       W16, WR16, WS16, c1b, c2b, rsb, skb, oXZ, oS);
  }
}

// Round 5
// 2061.334 us; speedup vs baseline: 2.7673x; 1.6848x over previous
//
#include <hip/hip_runtime.h>
#include <math.h>

typedef unsigned short u16;
typedef unsigned int u32;
typedef __attribute__((ext_vector_type(8))) short s8v;   // 8 bf16 (4 VGPR)
typedef __attribute__((ext_vector_type(4))) float f4v;   // mfma acc

// Problem constants
#define Bx 8
#define Cx 64
#define Nx 128
#define Tx 288
#define PL 12
#define CL 24
#define SP 12
#define TOUT 300
#define EPSV 0.01f
#define NTb 2359296L   // 8192*288 elems per batch

__device__ __forceinline__ float b2f(u16 h) {
  union { u32 u; float f; } v; v.u = ((u32)h) << 16; return v.f;
}
__device__ __forceinline__ u16 f2b(float f) {
  union { float f; u32 u; } v; v.f = f;
  return (u16)((v.u + 0x7FFFu + ((v.u >> 16) & 1u)) >> 16);  // RNE
}

// ---------------------------------------------------------------------------
// K0: adjacency  adjT[m][n] = softmax_m( emb[n]·emb[m] - 10*I ).  grid 128x64.
// ---------------------------------------------------------------------------
__global__ __launch_bounds__(64) void k0_adj(const float* __restrict__ emb,
                                             float* __restrict__ adjT) {
  int n = blockIdx.x;
  int lane = threadIdx.x;
  float d0 = 0.f, d1 = 0.f;
  for (int k = 0; k < 64; ++k) {
    float e = emb[n * 64 + k];
    d0 += e * emb[lane * 64 + k];
    d1 += e * emb[(lane + 64) * 64 + k];
  }
  if (lane == n) d0 -= 10.f;
  if (lane + 64 == n) d1 -= 10.f;
  float mx = fmaxf(d0, d1);
  for (int off = 32; off; off >>= 1) mx = fmaxf(mx, __shfl_xor(mx, off, 64));
  float e0 = expf(d0 - mx), e1 = expf(d1 - mx);
  float sm = e0 + e1;
  for (int off = 32; off; off >>= 1) sm += __shfl_xor(sm, off, 64);
  float inv = 1.f / sm;
  adjT[lane * 128 + n] = e0 * inv;
  adjT[(lane + 64) * 128 + n] = e1 * inv;
}

// ---------------------------------------------------------------------------
// Kw: weight prep (once), tiled for coalesced MFMA A-loads.
// W16[(j*4+kc)*4096 + R*32 + (k&31)] = bf16(cw[R][(j*64+cc)*2+tap]),
//   k = j*128 + (k&127), tap=(k&127)>>6, cc=k&63.  Rows 0..63=conv1, 64..127=conv2.
// WR16/WS16[(h*64+o)*32 + (k&31)] = 1x1 weights, h = k>>5.
// ---------------------------------------------------------------------------
__global__ __launch_bounds__(256) void k_wprep(
    const float* __restrict__ cw1, const float* __restrict__ cw2,
    const float* __restrict__ rsw, const float* __restrict__ skw,
    u16* __restrict__ W16, u16* __restrict__ WR16, u16* __restrict__ WS16) {
  int R = blockIdx.x;
  const float* src = (R < 64) ? (cw1 + (long)R * 1664) : (cw2 + (long)(R - 64) * 1664);
  for (int k = threadIdx.x; k < 1664; k += 256) {
    int j = k >> 7;
    int rem = k & 127;
    int tap = rem >> 6, cc = rem & 63;
    int kc = rem >> 5;
    W16[(j * 4 + kc) * 4096 + R * 32 + (rem & 31)] = f2b(src[(j * 64 + cc) * 2 + tap]);
  }
  if (R < 64) {
    for (int k = threadIdx.x; k < 64; k += 256) {
      int h = k >> 5;
      WR16[(h * 64 + R) * 32 + (k & 31)] = f2b(rsw[R * 64 + k]);
      WS16[(h * 64 + R) * 32 + (k & 31)] = f2b(skw[R * 64 + k]);
    }
  }
}

// ---------------------------------------------------------------------------
// K1: per-series norm chain, group-fused. One wave/series; 4/block.
// grid g*2048 x 256.  s is group-local.
// ---------------------------------------------------------------------------
__global__ __launch_bounds__(256) void k1_chain(
    const float* __restrict__ xb, float* __restrict__ ltm, float* __restrict__ lts,
    float* __restrict__ pm, float* __restrict__ ps, u16* __restrict__ stm,
    u16* __restrict__ sts, u16* __restrict__ x3, float* __restrict__ lastx1,
    float* __restrict__ lastx2) {
  __shared__ float lds[4 * 352];
  int tid = threadIdx.x;
  int wv = tid >> 6, lane = tid & 63;
  float* buf = lds + wv * 352;
  float* pat = buf + 288;
  long s = (long)blockIdx.x * 4 + wv;
  const float* xs = xb + s * Tx;

  float v[5];
  float sum = 0.f, sum2 = 0.f;
#pragma unroll
  for (int i = 0; i < 5; ++i) {
    int t = lane + 64 * i;
    if (t < Tx) { v[i] = xs[t]; sum += v[i]; sum2 += v[i] * v[i]; }
    else v[i] = 0.f;
  }
  for (int off = 32; off; off >>= 1) {
    sum += __shfl_xor(sum, off, 64);
    sum2 += __shfl_xor(sum2, off, 64);
  }
  float mean = sum * (1.f / 288.f);
  float var = sum2 * (1.f / 288.f) - mean * mean + 1e-5f;
  float sd = sqrtf(var);
  float r1 = rsqrtf(var + EPSV);
  if (lane == 0) { ltm[s] = mean; lts[s] = sd; }
#pragma unroll
  for (int i = 0; i < 5; ++i) {
    int t = lane + 64 * i;
    if (t < Tx) {
      float x1 = (v[i] - mean) * r1;
      v[i] = x1;
      buf[t] = x1;
      if (t >= Tx - SP) lastx1[s * SP + t - (Tx - SP)] = x1;
    }
  }
  __syncthreads();
  if (lane < CL) {
    float a = 0.f, b2 = 0.f;
    for (int k = 0; k < 12; ++k) {
      float u = buf[k * CL + lane];
      a += u; b2 += u * u;
    }
    float pmv = a * (1.f / 12.f);
    float pvar = b2 * (1.f / 12.f) - pmv * pmv + 1e-5f;
    float psd = sqrtf(pvar);
    pat[lane] = pmv; pat[CL + lane] = psd;
    pm[s * CL + lane] = pmv; ps[s * CL + lane] = psd;
  }
  __syncthreads();
  float w2v[5];
#pragma unroll
  for (int i = 0; i < 5; ++i) {
    int t = lane + 64 * i;
    if (t < Tx) {
      int l = t % CL;
      float pmv = pat[l], psd = pat[CL + l];
      float x2 = (v[i] - pmv) * rsqrtf(psd * psd + EPSV);
      w2v[i] = x2;
      if (t >= Tx - SP) lastx2[s * SP + t - (Tx - SP)] = x2;
    } else w2v[i] = 0.f;
  }
  __syncthreads();
#pragma unroll
  for (int i = 0; i < 5; ++i) {
    int t = lane + 64 * i;
    if (t < Tx) buf[t] = w2v[i];
  }
  __syncthreads();
#pragma unroll
  for (int i = 0; i < 5; ++i) {
    int t = lane + 64 * i;
    if (t < Tx) {
      int te = t < 11 ? 11 : t;
      float a = 0.f, b2 = 0.f;
#pragma unroll
      for (int jj = 0; jj < 12; ++jj) {
        float u = buf[te - 11 + jj];
        a += u; b2 += u * u;
      }
      float m = a * (1.f / 12.f);
      float varw = b2 * (1.f / 12.f) - m * m + 1e-5f;
      stm[s * Tx + t] = f2b(m);
      sts[s * Tx + t] = f2b(sqrtf(varw));
      x3[s * Tx + t] = f2b((w2v[i] - m) * rsqrtf(varw + EPSV));
    }
  }
}

// ---------------------------------------------------------------------------
// K2: spatial norm, group-fused. grid g*576 x 128 (c_ext = bid/9).
// ---------------------------------------------------------------------------
__global__ __launch_bounds__(128) void k2_spatial(
    const u16* __restrict__ x3, const float* __restrict__ adjT,
    u16* __restrict__ x4, u16* __restrict__ spm, u16* __restrict__ sps) {
  __shared__ float X[128 * 36];
  int bid = blockIdx.x;
  int tc = bid % 9;
  long c = bid / 9;
  int t0 = tc * 32;
  int tid = threadIdx.x;
  for (int idx = tid; idx < 128 * 32; idx += 128) {
    int m = idx >> 5, i = idx & 31;
    X[m * 36 + i] = b2f(x3[(c * 128 + m) * Tx + t0 + i]);
  }
  __syncthreads();
  float a1[32], a2[32];
#pragma unroll
  for (int i = 0; i < 32; ++i) { a1[i] = 0.f; a2[i] = 0.f; }
  for (int m = 0; m < 128; ++m) {
    float a = adjT[m * 128 + tid];
    const float4* xp = (const float4*)&X[m * 36];
#pragma unroll
    for (int ii = 0; ii < 8; ++ii) {
      float4 xq = xp[ii];
      float t0v = a * xq.x; a1[ii * 4 + 0] += t0v; a2[ii * 4 + 0] += t0v * xq.x;
      float t1v = a * xq.y; a1[ii * 4 + 1] += t1v; a2[ii * 4 + 1] += t1v * xq.y;
      float t2v = a * xq.z; a1[ii * 4 + 2] += t2v; a2[ii * 4 + 2] += t2v * xq.z;
      float t3v = a * xq.w; a1[ii * 4 + 3] += t3v; a2[ii * 4 + 3] += t3v * xq.w;
    }
  }
  long sOut = c * 128 + tid;
#pragma unroll
  for (int i = 0; i < 32; ++i) {
    float mean = a1[i];
    float varv = a2[i] - mean * mean + 1e-5f;
    float xv = X[tid * 36 + i];
    long off = sOut * Tx + t0 + i;
    x4[off] = f2b((xv - mean) * rsqrtf(varv + EPSV));
    spm[off] = f2b(mean);
    sps[off] = f2b(sqrtf(varv));
  }
}

// ---------------------------------------------------------------------------
// K3: residual-extrap tails, group-fused. grid g*512 x 256.
// bid: n = bid&127, j = (bid>>7)&3, b_loc = bid>>9.
// ---------------------------------------------------------------------------
__global__ __launch_bounds__(256) void k3_tails(
    const float* __restrict__ lastx1, const float* __restrict__ lastx2,
    const u16* __restrict__ x3, const u16* __restrict__ x4,
    const float* __restrict__ w0, const float* __restrict__ bb0,
    const float* __restrict__ w1, const float* __restrict__ bb1,
    const float* __restrict__ w2, const float* __restrict__ bb2,
    const float* __restrict__ w3, const float* __restrict__ bb3,
    float* __restrict__ tails) {
  __shared__ float S[768];
  int bid = blockIdx.x;
  int n = bid & 127;
  int j = (bid >> 7) & 3;
  int b_loc = bid >> 9;
  const float* W; const float* Bv;
  if (j == 0) { W = w0; Bv = bb0; }
  else if (j == 1) { W = w1; Bv = bb1; }
  else if (j == 2) { W = w2; Bv = bb2; }
  else { W = w3; Bv = bb3; }
  int tid = threadIdx.x;
  for (int idx = tid; idx < 768; idx += 256) {
    int cin = idx / 12, l = idx % 12;
    long s = (long)b_loc * 8192 + (long)cin * 128 + n;
    float val;
    if (j == 0) val = lastx1[s * 12 + l];
    else if (j == 1) val = lastx2[s * 12 + l];
    else if (j == 2) val = b2f(x3[s * Tx + (Tx - 12) + l]);
    else val = b2f(x4[s * Tx + (Tx - 12) + l]);
    S[idx] = val;
  }
  __syncthreads();
#pragma unroll
  for (int rep = 0; rep < 3; ++rep) {
    int o = tid + rep * 256;
    float acc = Bv[o];
    const float* wr = W + (long)o * 768;
#pragma unroll 8
    for (int q = 0; q < 768; q += 4) {
      float4 wq = *(const float4*)&wr[q];
      float4 sq = *(const float4*)&S[q];
      acc += wq.x * sq.x + wq.y * sq.y + wq.z * sq.z + wq.w * sq.w;
    }
    tails[(((long)b_loc * 4 + j) * 128 + n) * 768 + o] = acc;
  }
}

// ---------------------------------------------------------------------------
// xcat value generator (per j-block).
// ---------------------------------------------------------------------------
__device__ __forceinline__ float xcat_val(
    int j, int cc, int n, int tg,
    const float* __restrict__ xb, const float* __restrict__ ltm,
    const float* __restrict__ lts, const float* __restrict__ pm,
    const float* __restrict__ ps, const u16* __restrict__ stm,
    const u16* __restrict__ sts, const u16* __restrict__ x3,
    const u16* __restrict__ x4, const u16* __restrict__ spm,
    const u16* __restrict__ sps, const float* __restrict__ tails) {
  if (tg < 0 || tg >= TOUT) return 0.f;
  long s = (long)cc * 128 + n;
  int tcl = tg < Tx ? tg : (Tx - 1);
  switch (j) {
    case 0: return xb[s * Tx + tcl];
    case 1:
      if (tg < Tx) {
        float m = ltm[s], sdv = lts[s];
        return (xb[s * Tx + tg] - m) * rsqrtf(sdv * sdv + EPSV);
      }
      return tails[((long)0 * 128 + n) * 768 + (tg - Tx) * 64 + cc];
    case 2: return ltm[s];
    case 3: return lts[s];
    case 4:
      if (tg < Tx) {
        float m = ltm[s], sdv = lts[s];
        float x1 = (xb[s * Tx + tg] - m) * rsqrtf(sdv * sdv + EPSV);
        int l = tg % CL;
        float pmv = pm[s * CL + l], psd = ps[s * CL + l];
        return (x1 - pmv) * rsqrtf(psd * psd + EPSV);
      }
      return tails[((long)1 * 128 + n) * 768 + (tg - Tx) * 64 + cc];
    case 5: return pm[s * CL + tg % CL];
    case 6: return ps[s * CL + tg % CL];
    case 7:
      return (tg < Tx) ? b2f(x3[s * Tx + tg])
                       : tails[((long)2 * 128 + n) * 768 + (tg - Tx) * 64 + cc];
    case 8: return b2f(stm[s * Tx + tcl]);
    case 9: return b2f(sts[s * Tx + tcl]);
    case 10:
      return (tg < Tx) ? b2f(x4[s * Tx + tg])
                       : tails[((long)3 * 128 + n) * 768 + (tg - Tx) * 64 + cc];
    case 11: return b2f(spm[s * Tx + tcl]);
    default: return b2f(sps[s * Tx + tcl]);
  }
}

// ---------------------------------------------------------------------------
// K4 (MFMA), group-fused: M=128 rows x N=64 t x K=1664 per block + epilogue.
// grid g*640 x 256: n = bid&127; q = bid>>7; chunk = q%5; b_loc = q/5.
// Wave wv owns rows wv*32..wv*32+31 (no duplicate A fetch), all 64 t.
// LDS 26112 B -> 6 blocks/CU.
// ---------------------------------------------------------------------------
__global__ __launch_bounds__(256) void k4_mfma(
    const float* __restrict__ xbG, const float* __restrict__ ltmG,
    const float* __restrict__ ltsG, const float* __restrict__ pmG,
    const float* __restrict__ psG, const u16* __restrict__ stmG,
    const u16* __restrict__ stsG, const u16* __restrict__ x3G,
    const u16* __restrict__ x4G, const u16* __restrict__ spmG,
    const u16* __restrict__ spsG, const float* __restrict__ tailsG,
    const u16* __restrict__ W16, const u16* __restrict__ WR16,
    const u16* __restrict__ WS16, const float* __restrict__ cb1,
    const float* __restrict__ cb2, const float* __restrict__ rsb,
    const float* __restrict__ skb,
    float* __restrict__ outXZG, float* __restrict__ outSG) {
  __shared__ float smemf[6528];             // 26112 B
  u16* Bb = (u16*)smemf;                    // [64][136] bf16 (K-loop phase)
  float* abuf = smemf;                      // [64][66] f32 (epilogue)
  u16* zB = (u16*)(smemf + 4224);           // [64][72] bf16 (epilogue)

  int bid = blockIdx.x;
  int n = bid & 127;
  int q = bid >> 7;
  int b_loc = q / 5;
  int chunk = q - b_loc * 5;                // 0..4
  int t0 = chunk * 64;
  int tid = threadIdx.x;
  int wv = tid >> 6, lane = tid & 63;
  int rlane = lane & 15, glane = lane >> 4;
  int klane = glane * 8;

  // per-batch local pointers
  const float* xb  = xbG + b_loc * NTb;
  const float* ltm = ltmG + (long)b_loc * 8192;
  const float* lts = ltsG + (long)b_loc * 8192;
  const float* pm  = pmG + (long)b_loc * 8192 * CL;
  const float* ps  = psG + (long)b_loc * 8192 * CL;
  const u16* stm = stmG + b_loc * NTb;
  const u16* sts = stsG + b_loc * NTb;
  const u16* x3  = x3G + b_loc * NTb;
  const u16* x4  = x4G + b_loc * NTb;
  const u16* spm = spmG + b_loc * NTb;
  const u16* sps = spsG + b_loc * NTb;
  const float* tails = tailsG + (long)b_loc * 4 * 128 * 768;
  float* outXZ = outXZG + b_loc * NTb;
  float* outS  = outSG + (long)b_loc * 8192 * PL;

  // acc init with conv biases: wave rows = wv*32 + rt*16 + (glane*4 + reg)
  f4v acc[2][4];
#pragma unroll
  for (int rt = 0; rt < 2; ++rt) {
    int Rb = wv * 32 + rt * 16 + glane * 4;
#pragma unroll
    for (int reg = 0; reg < 4; ++reg) {
      int R = Rb + reg;
      float bv = (R < 64) ? cb1[R] : cb2[R - 64];
#pragma unroll
      for (int ct = 0; ct < 4; ++ct) acc[rt][ct][reg] = bv;
    }
  }

  for (int j = 0; j < 13; ++j) {
    __syncthreads();
    // ---- stage Bb: cc-pairs, u in 0..64 (tglob = t0-1+u) ----
    for (int idx = tid; idx < 32 * 65; idx += 256) {
      int ccp = idx / 65;
      int u = idx - ccp * 65;
      int cc0 = ccp * 2;
      int tg = t0 - 1 + u;
      float v0 = xcat_val(j, cc0, n, tg, xb, ltm, lts, pm, ps, stm, sts, x3, x4, spm, sps, tails);
      float v1 = xcat_val(j, cc0 + 1, n, tg, xb, ltm, lts, pm, ps, stm, sts, x3, x4, spm, sps, tails);
      u32 w = (u32)f2b(v0) | ((u32)f2b(v1) << 16);
      if (u >= 1) *(u32*)&Bb[(u - 1) * 136 + 64 + cc0] = w;   // tap1 (xcat[t])
      if (u < 64) *(u32*)&Bb[u * 136 + cc0] = w;              // tap0 (xcat[t-1])
    }
    __syncthreads();
    // ---- 4 k-steps of 32 ----
#pragma unroll
    for (int kc = 0; kc < 4; ++kc) {
      const u16* wj = W16 + (j * 4 + kc) * 4096;
      s8v av[2], bv[4];
#pragma unroll
      for (int rt = 0; rt < 2; ++rt) {
        int R = wv * 32 + rt * 16 + rlane;
        av[rt] = *(const s8v*)(wj + R * 32 + klane);
      }
#pragma unroll
      for (int ct = 0; ct < 4; ++ct) {
        int tl = ct * 16 + rlane;
        bv[ct] = *(const s8v*)(Bb + tl * 136 + kc * 32 + klane);
      }
#pragma unroll
      for (int rt = 0; rt < 2; ++rt)
#pragma unroll
        for (int ct = 0; ct < 4; ++ct)
          acc[rt][ct] = __builtin_amdgcn_mfma_f32_16x16x32_bf16(av[rt], bv[ct], acc[rt][ct], 0, 0, 0);
    }
  }

  // ---- epilogue: waves 2,3 hold conv2 rows -> abuf; waves 0,1 make z ----
  __syncthreads();
  if (wv >= 2) {
#pragma unroll
    for (int rt = 0; rt < 2; ++rt)
#pragma unroll
      for (int ct = 0; ct < 4; ++ct)
#pragma unroll
        for (int reg = 0; reg < 4; ++reg) {
          int r = (wv - 2) * 32 + rt * 16 + glane * 4 + reg;
          int tl = ct * 16 + rlane;
          abuf[r * 66 + tl] = acc[rt][ct][reg];
        }
  }
  __syncthreads();
  if (wv < 2) {
#pragma unroll
    for (int rt = 0; rt < 2; ++rt)
#pragma unroll
      for (int ct = 0; ct < 4; ++ct)
#pragma unroll
        for (int reg = 0; reg < 4; ++reg) {
          int r = wv * 32 + rt * 16 + glane * 4 + reg;
          int tl = ct * 16 + rlane;
          float a2v = abuf[r * 66 + tl];
          float z = tanhf(acc[rt][ct][reg]) * (1.f / (1.f + expf(-a2v)));
          zB[tl * 72 + r] = f2b(z);
        }
  }
  __syncthreads();
  // ---- out GEMM: wave wv -> o rows wv*16..+15, K=64, 4 t-tiles ----
  {
    int oL = wv * 16 + rlane;
    int oS = wv * 16 + glane * 4;
    s8v aR0 = *(const s8v*)(WR16 + oL * 32 + klane);
    s8v aR1 = *(const s8v*)(WR16 + 2048 + oL * 32 + klane);
    s8v aS0 = *(const s8v*)(WS16 + oL * 32 + klane);
    s8v aS1 = *(const s8v*)(WS16 + 2048 + oL * 32 + klane);
    for (int tt = 0; tt < 4; ++tt) {
      int tstart = t0 + tt * 16;
      if (tstart >= TOUT) break;
      bool res = tstart < Tx;
      s8v b0 = *(const s8v*)(zB + (tt * 16 + rlane) * 72 + klane);
      s8v b1 = *(const s8v*)(zB + (tt * 16 + rlane) * 72 + 32 + klane);
      f4v oa;
#pragma unroll
      for (int reg = 0; reg < 4; ++reg)
        oa[reg] = res ? rsb[oS + reg] : skb[oS + reg];
      if (res) {
        oa = __builtin_amdgcn_mfma_f32_16x16x32_bf16(aR0, b0, oa, 0, 0, 0);
        oa = __builtin_amdgcn_mfma_f32_16x16x32_bf16(aR1, b1, oa, 0, 0, 0);
        int tglob = tstart + rlane;
#pragma unroll
        for (int reg = 0; reg < 4; ++reg)
          outXZ[((long)(oS + reg) * 128 + n) * Tx + tglob] = oa[reg];
      } else {
        oa = __builtin_amdgcn_mfma_f32_16x16x32_bf16(aS0, b0, oa, 0, 0, 0);
        oa = __builtin_amdgcn_mfma_f32_16x16x32_bf16(aS1, b1, oa, 0, 0, 0);
        int tglob = tstart + rlane;
        if (tglob < TOUT) {
#pragma unroll
          for (int reg = 0; reg < 4; ++reg)
            outS[((long)(oS + reg) * 128 + n) * PL + (tglob - Tx)] = oa[reg];
        }
      }
    }
  }
}

// ---------------------------------------------------------------------------
extern "C" void kernel_launch(void* const* d_in, const int* in_sizes, int n_in,
                              void* d_out, int out_size, void* d_ws, size_t ws_size,
                              hipStream_t stream) {
  const float* x   = (const float*)d_in[0];
  const float* emb = (const float*)d_in[1];
  const float* rew[4] = {(const float*)d_in[2], (const float*)d_in[4],
                         (const float*)d_in[6], (const float*)d_in[8]};
  const float* reb[4] = {(const float*)d_in[3], (const float*)d_in[5],
                         (const float*)d_in[7], (const float*)d_in[9]};
  const float* c1w = (const float*)d_in[10];
  const float* c1b = (const float*)d_in[11];
  const float* c2w = (const float*)d_in[12];
  const float* c2b = (const float*)d_in[13];
  const float* skw = (const float*)d_in[14];
  const float* skb = (const float*)d_in[15];
  const float* rsw = (const float*)d_in[16];
  const float* rsb = (const float*)d_in[17];
  float* out = (float*)d_out;

  // shared region: adjT (64KB) + W16 (416KB) + WR16/WS16 (16KB)
  const size_t shared_bytes = 65536 + (52 * 4096 + 2 * 4096) * 2;   // 507904
  // per-batch: f32 999424*4 + u16 14155776*2 = 32,309,248 B
  const size_t per_batch = 999424UL * 4 + 14155776UL * 2;
  int g = 1;
  if (shared_bytes + 8 * per_batch + 4096 <= ws_size) g = 8;
  else if (shared_bytes + 4 * per_batch + 4096 <= ws_size) g = 4;
  else if (shared_bytes + 2 * per_batch + 4096 <= ws_size) g = 2;

  float* ws = (float*)d_ws;
  float* adjT = ws;                         // 16384 f32
  u16* W16  = (u16*)(adjT + 16384);         // 52*4096 u16
  u16* WR16 = W16 + 52 * 4096;              // 4096 u16
  u16* WS16 = WR16 + 4096;                  // 4096 u16
  float* fbase = (float*)(WS16 + 4096);
  float* ltm    = fbase;                    // g*8192
  float* lts    = ltm + (long)g * 8192;
  float* pmv    = lts + (long)g * 8192;     // g*8192*24
  float* psv    = pmv + (long)g * 8192 * CL;
  float* lastx1 = psv + (long)g * 8192 * CL;   // g*8192*12
  float* lastx2 = lastx1 + (long)g * 8192 * SP;
  float* tails  = lastx2 + (long)g * 8192 * SP;  // g*4*128*768
  u16* stm = (u16*)(tails + (long)g * 4 * 128 * 768);
  u16* sts = stm + (long)g * NTb;
  u16* x3  = sts + (long)g * NTb;
  u16* x4  = x3 + (long)g * NTb;
  u16* spm = x4 + (long)g * NTb;
  u16* sps = spm + (long)g * NTb;

  hipLaunchKernelGGL(k0_adj, dim3(128), dim3(64), 0, stream, emb, adjT);
  hipLaunchKernelGGL(k_wprep, dim3(128), dim3(256), 0, stream,
                     c1w, c2w, rsw, skw, W16, WR16, WS16);
  int ng = 8 / g;
  for (int gi = 0; gi < ng; ++gi) {
    long base = (long)gi * g;
    const float* xg = x + base * NTb;
    float* oXZ = out + base * NTb;
    float* oS  = out + (long)Bx * NTb + base * 8192 * PL;
    hipLaunchKernelGGL(k1_chain, dim3(g * 2048), dim3(256), 0, stream,
                       xg, ltm, lts, pmv, psv, stm, sts, x3, lastx1, lastx2);
    hipLaunchKernelGGL(k2_spatial, dim3(g * 576), dim3(128), 0, stream,
                       x3, adjT, x4, spm, sps);
    hipLaunchKernelGGL(k3_tails, dim3(g * 512), dim3(256), 0, stream,
                       lastx1, lastx2, x3, x4,
                       rew[0], reb[0], rew[1], reb[1],
                       rew[2], reb[2], rew[3], reb[3], tails);
    hipLaunchKernelGGL(k4_mfma, dim3(g * 640), dim3(256), 0, stream,
                       xg, ltm, lts, pmv, psv, stm, sts, x3, x4, spm, sps, tails,
                       W16, WR16, WS16, c1b, c2b, rsb, skb, oXZ, oS);
  }
}